// Round 5
// baseline (5157.105 us; speedup 1.0000x reference)
//
#include <hip/hip_runtime.h>
#include <stdint.h>

// Problem constants
#define NVOX   221184      // 2*48*48*48 voxels
#define NSTATE 7077888     // NVOX * 32 channels
// ws layout (floats):
//   [0, NSTATE)            stateA (f32)
//   [NSTATE, 2*NSTATE)     stateB (f32)
//   [2*NSTATE, +W_TOT)     weights (f32, transformed layouts)
//   [2*NSTATE + W_TOT]     dtype flag (u32: 1 = inputs bf16-packed, 0 = f32)
#define W_CWT 0
#define W_CB  6912
#define W_F0W 6928
#define W_F0B 13072
#define W_F1T 13200
#define W_TOT 17296

// ---------- bf16 helpers ----------
__host__ __device__ __forceinline__ float bf2f(unsigned short u) {
  union { uint32_t u; float f; } v; v.u = ((uint32_t)u) << 16; return v.f;
}
__device__ __forceinline__ unsigned short f2bf(float f) {  // RNE, finite values
  union { float f; uint32_t u; } v; v.f = f;
  uint32_t r = (v.u + 0x7FFFu + ((v.u >> 16) & 1u)) >> 16;
  return (unsigned short)r;
}
__device__ __forceinline__ float ldin(const void* p, int i, uint32_t bf) {
  return bf ? bf2f(((const unsigned short*)p)[i]) : ((const float*)p)[i];
}

// ---------- JAX Threefry-2x32 (20 rounds), bit-exact ----------
__host__ __device__ __forceinline__ void tf2x32(uint32_t k0, uint32_t k1,
                                                uint32_t x0, uint32_t x1,
                                                uint32_t& o0, uint32_t& o1) {
  uint32_t ks2 = k0 ^ k1 ^ 0x1BD11BDAu;
#define TFR(r) { x0 += x1; x1 = (x1 << r) | (x1 >> (32 - r)); x1 ^= x0; }
  x0 += k0; x1 += k1;
  TFR(13) TFR(15) TFR(26) TFR(6)
  x0 += k1;  x1 += ks2 + 1u;
  TFR(17) TFR(29) TFR(16) TFR(24)
  x0 += ks2; x1 += k0 + 2u;
  TFR(13) TFR(15) TFR(26) TFR(6)
  x0 += k0;  x1 += k1 + 3u;
  TFR(17) TFR(29) TFR(16) TFR(24)
  x0 += k1;  x1 += ks2 + 4u;
  TFR(13) TFR(15) TFR(26) TFR(6)
  x0 += ks2; x1 += k0 + 5u;
#undef TFR
  o0 = x0; o1 = x1;
}

// Partitionable-threefry mask (verified bit-exact in R3): counter=(0,vi),
// bits=r0^r1, keep (no fire) iff (bits>>9) > 2^22.
__device__ __forceinline__ float mask_val(uint32_t k0, uint32_t k1, uint32_t vi) {
  uint32_t r0, r1;
  tf2x32(k0, k1, 0u, vi, r0, r1);
  uint32_t bits = r0 ^ r1;
  return ((bits >> 9) > 0x400000u) ? 1.0f : 0.0f;
}

// ---------- dtype detector (verified in R3: flags f32) ----------
__global__ void nca_detect(const uint32_t* __restrict__ x, uint32_t* __restrict__ flag) {
  __shared__ int cnt[256];
  uint32_t w = x[threadIdx.x];
  uint32_t e = (w >> 7) & 0xFFu;
  cnt[threadIdx.x] = (e >= 110u && e <= 140u) ? 1 : 0;
  __syncthreads();
  for (int s = 128; s > 0; s >>= 1) {
    if ((int)threadIdx.x < s) cnt[threadIdx.x] += cnt[threadIdx.x + s];
    __syncthreads();
  }
  if (threadIdx.x == 0) *flag = (cnt[0] >= 160) ? 1u : 0u;
}

// ---------- weight prep ----------
__global__ __launch_bounds__(256) void nca_prep(
    const void* __restrict__ cw, const void* __restrict__ cb,
    const void* __restrict__ f0w, const void* __restrict__ f0b,
    const void* __restrict__ f1w, float* __restrict__ wb,
    const uint32_t* __restrict__ flagp) {
  uint32_t bf = *flagp;
  int e = blockIdx.x * 256 + threadIdx.x;
  if (e < 6912) {
    // cwT[t*256 + i*16 + o] = conv_w[o][i][t], t = kx*9+ky*3+kz (kx->h, ky->w, kz->d)
    int t = e >> 8, r = e & 255, i = r >> 4, o = r & 15;
    wb[W_CWT + e] = ldin(cw, o * 432 + i * 27 + t, bf);
  } else if (e < 6928) {
    wb[W_CB + (e - 6912)] = ldin(cb, e - 6912, bf);
  } else if (e < 13072) {
    wb[W_F0W + (e - 6928)] = ldin(f0w, e - 6928, bf);   // (128,48) row-major as-is
  } else if (e < 13200) {
    wb[W_F0B + (e - 13072)] = ldin(f0b, e - 13072, bf);
  } else if (e < W_TOT) {
    int r = e - 13200, c = r / 128, k = r % 128;         // fc1_w (32,128) -> f1T[k][c]
    wb[W_F1T + k * 32 + c] = ldin(f1w, r, bf);
  }
}

// ---------- init: state ch0..15 = x, ch16..31 = 0 ----------
__global__ __launch_bounds__(256) void nca_init(const void* __restrict__ x,
                                                float* __restrict__ st,
                                                const uint32_t* __restrict__ flagp) {
  uint32_t bf = *flagp;
  int gid = blockIdx.x * 256 + threadIdx.x;          // one voxel
  float v[32];
#pragma unroll
  for (int c = 0; c < 16; c++) v[c] = ldin(x, gid * 16 + c, bf);
#pragma unroll
  for (int c = 16; c < 32; c++) v[c] = 0.0f;
  float* po = st + (size_t)gid * 32;
#pragma unroll
  for (int c = 0; c < 32; c += 4)
    *(float4*)(po + c) = make_float4(v[c], v[c + 1], v[c + 2], v[c + 3]);
}

// ---------- one NCA step, 3D-tiled for L1 reuse ----------
// Block = 8x8x4 voxel tile (256 threads, 1 voxel/thread).
// __launch_bounds__(256, 4): grid is only 864 blocks = 3.375 blocks/CU, so
// guarantee 4 blocks/CU residency and raise the VGPR cap to 128 — the live
// set (din[48]+dx[32]+working ~100 regs) must NOT spill (R4: 60-VGPR cap from
// the default 8-wave occupancy target caused spill churn in the fc k-loop).
__global__ __launch_bounds__(256, 4) void nca_step(
    const float* __restrict__ sin, float* __restrict__ sout,
    const float* __restrict__ wb, uint32_t k0, uint32_t k1) {
  // block decode: bx = ((b*12 + tz)*6 + ty)*6 + tx
  int bx = blockIdx.x;
  int tx = bx % 6;  int r0 = bx / 6;
  int ty = r0 % 6;  int r1 = r0 / 6;
  int tz = r1 % 12; int b  = r1 / 12;
  int tid = threadIdx.x;
  int x = tid & 7, y = (tid >> 3) & 7, z = tid >> 6;
  int w = tx * 8 + x;
  int h = ty * 8 + y;
  int d = tz * 4 + z;
  int gid = ((b * 48 + d) * 48 + h) * 48 + w;

  const float* cwT = wb + W_CWT;
  const float* cbv = wb + W_CB;
  const float* f0w = wb + W_F0W;
  const float* f0b = wb + W_F0B;
  const float* f1T = wb + W_F1T;

  // din = [xc(16) | conv(16) | xm(16)]
  float din[48];
  const float* own = sin + (size_t)gid * 32;
#pragma unroll
  for (int c = 0; c < 16; c += 4) {
    float4 v = *(const float4*)(own + c);
    din[c] = v.x; din[c + 1] = v.y; din[c + 2] = v.z; din[c + 3] = v.w;
  }
#pragma unroll
  for (int c = 0; c < 16; c += 4) {
    float4 v = *(const float4*)(own + 16 + c);
    din[32 + c] = v.x; din[33 + c] = v.y; din[34 + c] = v.z; din[35 + c] = v.w;
  }
#pragma unroll
  for (int o = 0; o < 16; o++) din[16 + o] = cbv[o];

  // reflect indices (pad=1, mode='reflect': -1 -> 1, 48 -> 46)
  int dn[3], hn[3], wn[3];
  dn[0] = (d == 0) ? 1 : d - 1; dn[1] = d; dn[2] = (d == 47) ? 46 : d + 1;
  hn[0] = (h == 0) ? 1 : h - 1; hn[1] = h; hn[2] = (h == 47) ? 46 : h + 1;
  wn[0] = (w == 0) ? 1 : w - 1; wn[1] = w; wn[2] = (w == 47) ? 46 : w + 1;

  // tap loop: kz (d-offset) OUTER for L1 plane locality; weight tap index
  // t = kx*9 + ky*3 + kz  (kx->h, ky->w, kz->d) — verified in R3.
  for (int kz = 0; kz < 3; kz++) {
    const float* plane = sin + (((size_t)b * 48 + dn[kz]) * 48) * 48 * 32;
#pragma unroll
    for (int kx = 0; kx < 3; kx++) {
      const float* row = plane + (size_t)hn[kx] * 48 * 32;
#pragma unroll
      for (int ky = 0; ky < 3; ky++) {
        const float* nb = row + (size_t)wn[ky] * 32;
        const float* wt = cwT + (kx * 9 + ky * 3 + kz) * 256;   // [i][o]
#pragma unroll
        for (int i = 0; i < 16; i += 4) {
          float4 xv = *(const float4*)(nb + i);
#pragma unroll
          for (int o = 0; o < 16; o++) {
            din[16 + o] += wt[(i + 0) * 16 + o] * xv.x;
            din[16 + o] += wt[(i + 1) * 16 + o] * xv.y;
            din[16 + o] += wt[(i + 2) * 16 + o] * xv.z;
            din[16 + o] += wt[(i + 3) * 16 + o] * xv.w;
          }
        }
      }
    }
  }

  // fc0 (relu) fused with fc1 accumulation (weights via wave-uniform s_loads)
  float dx[32];
#pragma unroll
  for (int c = 0; c < 32; c++) dx[c] = 0.0f;
  for (int k = 0; k < 128; k++) {
    const float* w0 = f0w + k * 48;
    float h0 = f0b[k], h1 = 0.0f, h2 = 0.0f, h3 = 0.0f;
#pragma unroll
    for (int c = 0; c < 48; c += 4) {
      h0 += w0[c + 0] * din[c + 0];
      h1 += w0[c + 1] * din[c + 1];
      h2 += w0[c + 2] * din[c + 2];
      h3 += w0[c + 3] * din[c + 3];
    }
    float hk = fmaxf((h0 + h1) + (h2 + h3), 0.0f);
    const float* w1 = f1T + k * 32;
#pragma unroll
    for (int c = 0; c < 32; c++) dx[c] += w1[c] * hk;
  }

  // stochastic residual update; channel 0 frozen to OLD state
  float m = mask_val(k0, k1, (uint32_t)gid);
  float outv[32];
  outv[0] = din[0];
#pragma unroll
  for (int c = 1; c < 16; c++)  outv[c] = fmaf(dx[c], m, din[c]);        // xc
#pragma unroll
  for (int c = 16; c < 32; c++) outv[c] = fmaf(dx[c], m, din[c + 16]);   // xm
  float* po = sout + (size_t)gid * 32;
#pragma unroll
  for (int c = 0; c < 32; c += 4)
    *(float4*)(po + c) = make_float4(outv[c], outv[c + 1], outv[c + 2], outv[c + 3]);
}

// ---------- final f32 state -> output (dtype per flag) ----------
__global__ __launch_bounds__(256) void nca_out(const float* __restrict__ st,
                                               void* __restrict__ out,
                                               const uint32_t* __restrict__ flagp) {
  uint32_t bf = *flagp;
  int gid = blockIdx.x * 256 + threadIdx.x;           // 4 elems/thread
  float4 v = *(const float4*)(st + (size_t)gid * 4);
  if (bf) {
    ushort4 u;
    u.x = f2bf(v.x); u.y = f2bf(v.y); u.z = f2bf(v.z); u.w = f2bf(v.w);
    *(ushort4*)((unsigned short*)out + (size_t)gid * 4) = u;
  } else {
    *(float4*)((float*)out + (size_t)gid * 4) = v;
  }
}

extern "C" void kernel_launch(void* const* d_in, const int* in_sizes, int n_in,
                              void* d_out, int out_size, void* d_ws, size_t ws_size,
                              hipStream_t stream) {
  float* ws = (float*)d_ws;
  float* sA = ws;
  float* sB = ws + NSTATE;
  float* wb = ws + 2 * NSTATE;
  uint32_t* flag = (uint32_t*)(ws + 2 * NSTATE + W_TOT);

  nca_detect<<<1, 256, 0, stream>>>((const uint32_t*)d_in[0], flag);
  nca_prep<<<68, 256, 0, stream>>>(d_in[1], d_in[2], d_in[3], d_in[4], d_in[5], wb, flag);
  nca_init<<<NVOX / 256, 256, 0, stream>>>(d_in[0], sA, flag);

  float* src = sA;
  float* dst = sB;
  for (int s = 0; s < 10; s++) {
    uint32_t o0, o1;
    tf2x32(0u, 42u, 0u, (uint32_t)s, o0, o1);   // folded step key, host-side
    nca_step<<<864, 256, 0, stream>>>(src, dst, wb, o0, o1);
    float* tmp = src; src = dst; dst = tmp;
  }
  nca_out<<<NSTATE / 4 / 256, 256, 0, stream>>>(src, d_out, flag);
}

// Round 6
// 3868.944 us; speedup vs baseline: 1.3329x; 1.3329x over previous
//
#include <hip/hip_runtime.h>
#include <stdint.h>

// Problem constants
#define NVOX   221184      // 2*48*48*48 voxels
#define NSTATE 7077888     // NVOX * 32 channels
// ws layout (floats):
//   [0, NSTATE)            stateA (f32)
//   [NSTATE, 2*NSTATE)     stateB (f32)
//   [2*NSTATE, +W_TOT)     weights (f32, transformed layouts)
//   [2*NSTATE + W_TOT]     dtype flag (u32: 1 = inputs bf16-packed, 0 = f32)
#define W_CWT 0
#define W_CB  6912
#define W_F0W 6928        // fc0_w[128][48] ........ 6144 floats   } staged to LDS
#define W_F0B 13072       // fc0_b[128] ............  128 floats   } (contiguous
#define W_F1T 13200       // fc1T[128][32] ......... 4096 floats   }  10368 floats)
#define W_TOT 17296

// LDS layout (floats): [0,6144) fc0_w | [6144,6272) fc0_b | [6272,10368) fc1T
#define S_F0W 0
#define S_F0B 6144
#define S_F1T 6272
#define S_TOT 10368

// ---------- bf16 helpers ----------
__host__ __device__ __forceinline__ float bf2f(unsigned short u) {
  union { uint32_t u; float f; } v; v.u = ((uint32_t)u) << 16; return v.f;
}
__device__ __forceinline__ unsigned short f2bf(float f) {  // RNE, finite values
  union { float f; uint32_t u; } v; v.f = f;
  uint32_t r = (v.u + 0x7FFFu + ((v.u >> 16) & 1u)) >> 16;
  return (unsigned short)r;
}
__device__ __forceinline__ float ldin(const void* p, int i, uint32_t bf) {
  return bf ? bf2f(((const unsigned short*)p)[i]) : ((const float*)p)[i];
}

// ---------- JAX Threefry-2x32 (20 rounds), bit-exact ----------
__host__ __device__ __forceinline__ void tf2x32(uint32_t k0, uint32_t k1,
                                                uint32_t x0, uint32_t x1,
                                                uint32_t& o0, uint32_t& o1) {
  uint32_t ks2 = k0 ^ k1 ^ 0x1BD11BDAu;
#define TFR(r) { x0 += x1; x1 = (x1 << r) | (x1 >> (32 - r)); x1 ^= x0; }
  x0 += k0; x1 += k1;
  TFR(13) TFR(15) TFR(26) TFR(6)
  x0 += k1;  x1 += ks2 + 1u;
  TFR(17) TFR(29) TFR(16) TFR(24)
  x0 += ks2; x1 += k0 + 2u;
  TFR(13) TFR(15) TFR(26) TFR(6)
  x0 += k0;  x1 += k1 + 3u;
  TFR(17) TFR(29) TFR(16) TFR(24)
  x0 += k1;  x1 += ks2 + 4u;
  TFR(13) TFR(15) TFR(26) TFR(6)
  x0 += ks2; x1 += k0 + 5u;
#undef TFR
  o0 = x0; o1 = x1;
}

// Partitionable-threefry mask (verified bit-exact in R3): counter=(0,vi),
// bits=r0^r1, keep (no fire) iff (bits>>9) > 2^22.
__device__ __forceinline__ float mask_val(uint32_t k0, uint32_t k1, uint32_t vi) {
  uint32_t r0, r1;
  tf2x32(k0, k1, 0u, vi, r0, r1);
  uint32_t bits = r0 ^ r1;
  return ((bits >> 9) > 0x400000u) ? 1.0f : 0.0f;
}

// ---------- dtype detector (verified in R3: flags f32) ----------
__global__ void nca_detect(const uint32_t* __restrict__ x, uint32_t* __restrict__ flag) {
  __shared__ int cnt[256];
  uint32_t w = x[threadIdx.x];
  uint32_t e = (w >> 7) & 0xFFu;
  cnt[threadIdx.x] = (e >= 110u && e <= 140u) ? 1 : 0;
  __syncthreads();
  for (int s = 128; s > 0; s >>= 1) {
    if ((int)threadIdx.x < s) cnt[threadIdx.x] += cnt[threadIdx.x + s];
    __syncthreads();
  }
  if (threadIdx.x == 0) *flag = (cnt[0] >= 160) ? 1u : 0u;
}

// ---------- weight prep ----------
__global__ __launch_bounds__(256) void nca_prep(
    const void* __restrict__ cw, const void* __restrict__ cb,
    const void* __restrict__ f0w, const void* __restrict__ f0b,
    const void* __restrict__ f1w, float* __restrict__ wb,
    const uint32_t* __restrict__ flagp) {
  uint32_t bf = *flagp;
  int e = blockIdx.x * 256 + threadIdx.x;
  if (e < 6912) {
    // cwT[t*256 + i*16 + o] = conv_w[o][i][t], t = kx*9+ky*3+kz (kx->h, ky->w, kz->d)
    int t = e >> 8, r = e & 255, i = r >> 4, o = r & 15;
    wb[W_CWT + e] = ldin(cw, o * 432 + i * 27 + t, bf);
  } else if (e < 6928) {
    wb[W_CB + (e - 6912)] = ldin(cb, e - 6912, bf);
  } else if (e < 13072) {
    wb[W_F0W + (e - 6928)] = ldin(f0w, e - 6928, bf);   // (128,48) row-major as-is
  } else if (e < 13200) {
    wb[W_F0B + (e - 13072)] = ldin(f0b, e - 13072, bf);
  } else if (e < W_TOT) {
    int r = e - 13200, c = r / 128, k = r % 128;         // fc1_w (32,128) -> f1T[k][c]
    wb[W_F1T + k * 32 + c] = ldin(f1w, r, bf);
  }
}

// ---------- init: state ch0..15 = x, ch16..31 = 0 ----------
__global__ __launch_bounds__(256) void nca_init(const void* __restrict__ x,
                                                float* __restrict__ st,
                                                const uint32_t* __restrict__ flagp) {
  uint32_t bf = *flagp;
  int gid = blockIdx.x * 256 + threadIdx.x;          // one voxel
  float v[32];
#pragma unroll
  for (int c = 0; c < 16; c++) v[c] = ldin(x, gid * 16 + c, bf);
#pragma unroll
  for (int c = 16; c < 32; c++) v[c] = 0.0f;
  float* po = st + (size_t)gid * 32;
#pragma unroll
  for (int c = 0; c < 32; c += 4)
    *(float4*)(po + c) = make_float4(v[c], v[c + 1], v[c + 2], v[c + 3]);
}

// ---------- one NCA step, 3D-tiled, fc weights in LDS ----------
// Block = 8x8x4 voxel tile (256 threads, 1 voxel/thread).
// R4/R5 evidence: fc k-loop serialized on s_load weight chains (SGPR-limited,
// VALUBusy pinned ~26%); launch_bounds(256,4) made the allocator split the
// unified file 64 arch + AGPR spills (VALUBusy 63%, 2.5x slower) — so:
//  * fc weights (41.5 KB, contiguous) staged in LDS -> broadcast ds_read,
//    deep lgkm pipelining, no SGPR pressure;
//  * __launch_bounds__(256,3): ~170-VGPR budget >= ~120 live set, 3 blocks/CU
//    (LDS 3x41.5 = 124.5 KB <= 160), matching the 864-block grid (3.375/CU).
__global__ __launch_bounds__(256, 3) void nca_step(
    const float* __restrict__ sin, float* __restrict__ sout,
    const float* __restrict__ wb, uint32_t k0, uint32_t k1) {
  __shared__ float smem[S_TOT];
  {
    const float4* gsrc = (const float4*)(wb + W_F0W);   // 6928 floats = 16B-aligned
    float4* sdst = (float4*)smem;
    for (int i = threadIdx.x; i < S_TOT / 4; i += 256) sdst[i] = gsrc[i];
  }

  // block decode: bx = ((b*12 + tz)*6 + ty)*6 + tx
  int bx = blockIdx.x;
  int tx = bx % 6;  int r0 = bx / 6;
  int ty = r0 % 6;  int r1 = r0 / 6;
  int tz = r1 % 12; int b  = r1 / 12;
  int tid = threadIdx.x;
  int x = tid & 7, y = (tid >> 3) & 7, z = tid >> 6;
  int w = tx * 8 + x;
  int h = ty * 8 + y;
  int d = tz * 4 + z;
  int gid = ((b * 48 + d) * 48 + h) * 48 + w;

  const float* cwT = wb + W_CWT;
  const float* cbv = wb + W_CB;

  // din = [xc(16) | conv(16) | xm(16)]
  float din[48];
  const float* own = sin + (size_t)gid * 32;
#pragma unroll
  for (int c = 0; c < 16; c += 4) {
    float4 v = *(const float4*)(own + c);
    din[c] = v.x; din[c + 1] = v.y; din[c + 2] = v.z; din[c + 3] = v.w;
  }
#pragma unroll
  for (int c = 0; c < 16; c += 4) {
    float4 v = *(const float4*)(own + 16 + c);
    din[32 + c] = v.x; din[33 + c] = v.y; din[34 + c] = v.z; din[35 + c] = v.w;
  }
#pragma unroll
  for (int o = 0; o < 16; o++) din[16 + o] = cbv[o];

  // reflect indices (pad=1, mode='reflect': -1 -> 1, 48 -> 46)
  int dn[3], hn[3], wn[3];
  dn[0] = (d == 0) ? 1 : d - 1; dn[1] = d; dn[2] = (d == 47) ? 46 : d + 1;
  hn[0] = (h == 0) ? 1 : h - 1; hn[1] = h; hn[2] = (h == 47) ? 46 : h + 1;
  wn[0] = (w == 0) ? 1 : w - 1; wn[1] = w; wn[2] = (w == 47) ? 46 : w + 1;

  // tap loop, fully unrolled: t = kx*9 + ky*3 + kz (kx->h, ky->w, kz->d) — R3-verified.
#pragma unroll
  for (int kz = 0; kz < 3; kz++) {
    const float* plane = sin + (((size_t)b * 48 + dn[kz]) * 48) * 48 * 32;
#pragma unroll
    for (int kx = 0; kx < 3; kx++) {
      const float* row = plane + (size_t)hn[kx] * 48 * 32;
#pragma unroll
      for (int ky = 0; ky < 3; ky++) {
        const float* nb = row + (size_t)wn[ky] * 32;
        const float* wt = cwT + (kx * 9 + ky * 3 + kz) * 256;   // [i][o]
#pragma unroll
        for (int i = 0; i < 16; i += 4) {
          float4 xv = *(const float4*)(nb + i);
#pragma unroll
          for (int o = 0; o < 16; o++) {
            din[16 + o] += wt[(i + 0) * 16 + o] * xv.x;
            din[16 + o] += wt[(i + 1) * 16 + o] * xv.y;
            din[16 + o] += wt[(i + 2) * 16 + o] * xv.z;
            din[16 + o] += wt[(i + 3) * 16 + o] * xv.w;
          }
        }
      }
    }
  }

  __syncthreads();   // LDS weights ready (staged at top, overlapped with conv)

  // fc0 (relu) fused with fc1 accumulation — weights broadcast from LDS
  float dx[32];
#pragma unroll
  for (int c = 0; c < 32; c++) dx[c] = 0.0f;
  for (int k = 0; k < 128; k++) {
    const float* w0 = smem + S_F0W + k * 48;
    float h0 = smem[S_F0B + k], h1 = 0.0f, h2 = 0.0f, h3 = 0.0f;
#pragma unroll
    for (int c = 0; c < 48; c += 4) {
      h0 += w0[c + 0] * din[c + 0];
      h1 += w0[c + 1] * din[c + 1];
      h2 += w0[c + 2] * din[c + 2];
      h3 += w0[c + 3] * din[c + 3];
    }
    float hk = fmaxf((h0 + h1) + (h2 + h3), 0.0f);
    const float* w1 = smem + S_F1T + k * 32;
#pragma unroll
    for (int c = 0; c < 32; c++) dx[c] += w1[c] * hk;
  }

  // stochastic residual update; channel 0 frozen to OLD state
  float m = mask_val(k0, k1, (uint32_t)gid);
  float outv[32];
  outv[0] = din[0];
#pragma unroll
  for (int c = 1; c < 16; c++)  outv[c] = fmaf(dx[c], m, din[c]);        // xc
#pragma unroll
  for (int c = 16; c < 32; c++) outv[c] = fmaf(dx[c], m, din[c + 16]);   // xm
  float* po = sout + (size_t)gid * 32;
#pragma unroll
  for (int c = 0; c < 32; c += 4)
    *(float4*)(po + c) = make_float4(outv[c], outv[c + 1], outv[c + 2], outv[c + 3]);
}

// ---------- final f32 state -> output (dtype per flag) ----------
__global__ __launch_bounds__(256) void nca_out(const float* __restrict__ st,
                                               void* __restrict__ out,
                                               const uint32_t* __restrict__ flagp) {
  uint32_t bf = *flagp;
  int gid = blockIdx.x * 256 + threadIdx.x;           // 4 elems/thread
  float4 v = *(const float4*)(st + (size_t)gid * 4);
  if (bf) {
    ushort4 u;
    u.x = f2bf(v.x); u.y = f2bf(v.y); u.z = f2bf(v.z); u.w = f2bf(v.w);
    *(ushort4*)((unsigned short*)out + (size_t)gid * 4) = u;
  } else {
    *(float4*)((float*)out + (size_t)gid * 4) = v;
  }
}

extern "C" void kernel_launch(void* const* d_in, const int* in_sizes, int n_in,
                              void* d_out, int out_size, void* d_ws, size_t ws_size,
                              hipStream_t stream) {
  float* ws = (float*)d_ws;
  float* sA = ws;
  float* sB = ws + NSTATE;
  float* wb = ws + 2 * NSTATE;
  uint32_t* flag = (uint32_t*)(ws + 2 * NSTATE + W_TOT);

  nca_detect<<<1, 256, 0, stream>>>((const uint32_t*)d_in[0], flag);
  nca_prep<<<68, 256, 0, stream>>>(d_in[1], d_in[2], d_in[3], d_in[4], d_in[5], wb, flag);
  nca_init<<<NVOX / 256, 256, 0, stream>>>(d_in[0], sA, flag);

  float* src = sA;
  float* dst = sB;
  for (int s = 0; s < 10; s++) {
    uint32_t o0, o1;
    tf2x32(0u, 42u, 0u, (uint32_t)s, o0, o1);   // folded step key, host-side
    nca_step<<<864, 256, 0, stream>>>(src, dst, wb, o0, o1);
    float* tmp = src; src = dst; dst = tmp;
  }
  nca_out<<<NSTATE / 4 / 256, 256, 0, stream>>>(src, d_out, flag);
}

// Round 7
// 1829.766 us; speedup vs baseline: 2.8185x; 2.1144x over previous
//
#include <hip/hip_runtime.h>
#include <stdint.h>

// Problem constants
#define NVOX   221184      // 2*48*48*48 voxels
#define NSTATE 7077888     // NVOX * 32 channels
// ws layout (floats):
//   [0, NSTATE)            stateA (f32)
//   [NSTATE, 2*NSTATE)     stateB (f32)
//   [2*NSTATE, +W_TOT)     weights (f32, transformed layouts)
//   [2*NSTATE + W_TOT]     dtype flag (u32: 1 = inputs bf16-packed, 0 = f32)
#define W_CWT 0
#define W_CB  6912
#define W_F0W 6928
#define W_F0B 13072
#define W_F1T 13200
#define W_TOT 17296

// ---------- bf16 helpers ----------
__host__ __device__ __forceinline__ float bf2f(unsigned short u) {
  union { uint32_t u; float f; } v; v.u = ((uint32_t)u) << 16; return v.f;
}
__device__ __forceinline__ unsigned short f2bf(float f) {  // RNE, finite values
  union { float f; uint32_t u; } v; v.f = f;
  uint32_t r = (v.u + 0x7FFFu + ((v.u >> 16) & 1u)) >> 16;
  return (unsigned short)r;
}
__device__ __forceinline__ float ldin(const void* p, int i, uint32_t bf) {
  return bf ? bf2f(((const unsigned short*)p)[i]) : ((const float*)p)[i];
}

// ---------- JAX Threefry-2x32 (20 rounds), bit-exact ----------
__host__ __device__ __forceinline__ void tf2x32(uint32_t k0, uint32_t k1,
                                                uint32_t x0, uint32_t x1,
                                                uint32_t& o0, uint32_t& o1) {
  uint32_t ks2 = k0 ^ k1 ^ 0x1BD11BDAu;
#define TFR(r) { x0 += x1; x1 = (x1 << r) | (x1 >> (32 - r)); x1 ^= x0; }
  x0 += k0; x1 += k1;
  TFR(13) TFR(15) TFR(26) TFR(6)
  x0 += k1;  x1 += ks2 + 1u;
  TFR(17) TFR(29) TFR(16) TFR(24)
  x0 += ks2; x1 += k0 + 2u;
  TFR(13) TFR(15) TFR(26) TFR(6)
  x0 += k0;  x1 += k1 + 3u;
  TFR(17) TFR(29) TFR(16) TFR(24)
  x0 += k1;  x1 += ks2 + 4u;
  TFR(13) TFR(15) TFR(26) TFR(6)
  x0 += ks2; x1 += k0 + 5u;
#undef TFR
  o0 = x0; o1 = x1;
}

// Partitionable-threefry mask (verified bit-exact in R3): counter=(0,vi),
// bits=r0^r1, keep (no fire) iff (bits>>9) > 2^22.
__device__ __forceinline__ float mask_val(uint32_t k0, uint32_t k1, uint32_t vi) {
  uint32_t r0, r1;
  tf2x32(k0, k1, 0u, vi, r0, r1);
  uint32_t bits = r0 ^ r1;
  return ((bits >> 9) > 0x400000u) ? 1.0f : 0.0f;
}

// ---------- dtype detector (verified in R3: flags f32) ----------
__global__ void nca_detect(const uint32_t* __restrict__ x, uint32_t* __restrict__ flag) {
  __shared__ int cnt[256];
  uint32_t w = x[threadIdx.x];
  uint32_t e = (w >> 7) & 0xFFu;
  cnt[threadIdx.x] = (e >= 110u && e <= 140u) ? 1 : 0;
  __syncthreads();
  for (int s = 128; s > 0; s >>= 1) {
    if ((int)threadIdx.x < s) cnt[threadIdx.x] += cnt[threadIdx.x + s];
    __syncthreads();
  }
  if (threadIdx.x == 0) *flag = (cnt[0] >= 160) ? 1u : 0u;
}

// ---------- weight prep ----------
__global__ __launch_bounds__(256) void nca_prep(
    const void* __restrict__ cw, const void* __restrict__ cb,
    const void* __restrict__ f0w, const void* __restrict__ f0b,
    const void* __restrict__ f1w, float* __restrict__ wb,
    const uint32_t* __restrict__ flagp) {
  uint32_t bf = *flagp;
  int e = blockIdx.x * 256 + threadIdx.x;
  if (e < 6912) {
    // cwT[t*256 + i*16 + o] = conv_w[o][i][t], t = kx*9+ky*3+kz (kx->h, ky->w, kz->d)
    int t = e >> 8, r = e & 255, i = r >> 4, o = r & 15;
    wb[W_CWT + e] = ldin(cw, o * 432 + i * 27 + t, bf);
  } else if (e < 6928) {
    wb[W_CB + (e - 6912)] = ldin(cb, e - 6912, bf);
  } else if (e < 13072) {
    wb[W_F0W + (e - 6928)] = ldin(f0w, e - 6928, bf);   // (128,48) row-major as-is
  } else if (e < 13200) {
    wb[W_F0B + (e - 13072)] = ldin(f0b, e - 13072, bf);
  } else if (e < W_TOT) {
    int r = e - 13200, c = r / 128, k = r % 128;         // fc1_w (32,128) -> f1T[k][c]
    wb[W_F1T + k * 32 + c] = ldin(f1w, r, bf);
  }
}

// ---------- init: state ch0..15 = x, ch16..31 = 0 ----------
__global__ __launch_bounds__(256) void nca_init(const void* __restrict__ x,
                                                float* __restrict__ st,
                                                const uint32_t* __restrict__ flagp) {
  uint32_t bf = *flagp;
  int gid = blockIdx.x * 256 + threadIdx.x;          // one voxel
  float v[32];
#pragma unroll
  for (int c = 0; c < 16; c++) v[c] = ldin(x, gid * 16 + c, bf);
#pragma unroll
  for (int c = 16; c < 32; c++) v[c] = 0.0f;
  float* po = st + (size_t)gid * 32;
#pragma unroll
  for (int c = 0; c < 32; c += 4)
    *(float4*)(po + c) = make_float4(v[c], v[c + 1], v[c + 2], v[c + 3]);
}

// ---------- one NCA step, V=2 voxels/thread (d-paired) ----------
// R4-R6 evidence: kernel is weight-operand-delivery bound (VALU idle ~75%
// waiting on s_load chains; FMA:weight-dword ratio was 1:1 and the ~60-SGPR
// prefetch window can't cover K$ latency). V=2 doubles the ratio and the
// latency cover. d-pairing lets 4 plane-loads serve both voxels' 3 kz-taps.
// __launch_bounds__(256,2): 256-VGPR cap for the ~180-reg live set
// (R5 lesson: a 128 cap forces 64-arch + AGPR-spill churn — 2.5x slower).
__global__ __launch_bounds__(256, 2) void nca_step(
    const float* __restrict__ sin, float* __restrict__ sout,
    const float* __restrict__ wb, uint32_t k0, uint32_t k1) {
  // block decode: bx = ((b*6 + tdz)*6 + ty)*6 + tx ; 432 blocks total
  int bx = blockIdx.x;
  int tx  = bx % 6;  int r0i = bx / 6;
  int ty  = r0i % 6; int r1i = r0i / 6;
  int tdz = r1i % 6; int b   = r1i / 6;
  int tid = threadIdx.x;
  int x = tid & 7, y = (tid >> 3) & 7, z = tid >> 6;   // 8 x 8 x 4 threads
  int w  = tx * 8 + x;
  int h  = ty * 8 + y;
  int d0 = (tdz * 4 + z) * 2;                          // even, 0..46
  int d1 = d0 + 1;
  int gid0 = ((b * 48 + d0) * 48 + h) * 48 + w;
  int gid1 = gid0 + 2304;                              // +1 plane (48*48)

  const float* cwT = wb + W_CWT;
  const float* cbv = wb + W_CB;
  const float* f0w = wb + W_F0W;
  const float* f0b = wb + W_F0B;
  const float* f1T = wb + W_F1T;

  // own-state xc (kept live: conv input + fc input + residual base)
  float xc0[16], xc1[16];
  {
    const float* o0p = sin + (size_t)gid0 * 32;
    const float* o1p = sin + (size_t)gid1 * 32;
#pragma unroll
    for (int c = 0; c < 16; c += 4) {
      float4 v0 = *(const float4*)(o0p + c);
      float4 v1 = *(const float4*)(o1p + c);
      xc0[c] = v0.x; xc0[c+1] = v0.y; xc0[c+2] = v0.z; xc0[c+3] = v0.w;
      xc1[c] = v1.x; xc1[c+1] = v1.y; xc1[c+2] = v1.z; xc1[c+3] = v1.w;
    }
  }

  // conv accumulators (bias-init)
  float cv0[16], cv1[16];
#pragma unroll
  for (int o = 0; o < 16; o++) { cv0[o] = cbv[o]; cv1[o] = cbv[o]; }

  // reflect indices (pad=1, 'reflect': -1 -> 1, 48 -> 46)
  int hm = (h == 0) ? 1 : h - 1, hp = (h == 47) ? 46 : h + 1;
  int wm = (w == 0) ? 1 : w - 1, wp = (w == 47) ? 46 : w + 1;
  // 4 d-planes serving both voxels: v0 tap kz -> P[kz], v1 tap kz -> P[kz+1]
  int P0 = (d0 == 0) ? 1 : d0 - 1;
  int P1 = d0;
  int P2 = d1;
  int P3 = (d1 == 47) ? 46 : d1 + 1;

  const size_t bbase = (size_t)b * 48;
  for (int kxy = 0; kxy < 9; kxy++) {
    int kx = kxy / 3, ky = kxy % 3;
    int hh = (kx == 0) ? hm : ((kx == 1) ? h : hp);
    int ww = (ky == 0) ? wm : ((ky == 1) ? w : wp);
    size_t rw = (size_t)hh * 48 + ww;
    const float* r0 = sin + (((bbase + P0) * 48) * 48 + rw) * 32;
    const float* r1 = sin + (((bbase + P1) * 48) * 48 + rw) * 32;
    const float* r2 = sin + (((bbase + P2) * 48) * 48 + rw) * 32;
    const float* r3 = sin + (((bbase + P3) * 48) * 48 + rw) * 32;
    for (int i = 0; i < 16; i += 4) {
      float4 a0 = *(const float4*)(r0 + i);
      float4 a1 = *(const float4*)(r1 + i);
      float4 a2 = *(const float4*)(r2 + i);
      float4 a3 = *(const float4*)(r3 + i);
      float xr[4][4] = {{a0.x,a0.y,a0.z,a0.w}, {a1.x,a1.y,a1.z,a1.w},
                        {a2.x,a2.y,a2.z,a2.w}, {a3.x,a3.y,a3.z,a3.w}};
#pragma unroll
      for (int kz = 0; kz < 3; kz++) {
        const float* wt = cwT + (kx * 9 + ky * 3 + kz) * 256 + i * 16;
#pragma unroll
        for (int j = 0; j < 4; j++) {
#pragma unroll
          for (int o = 0; o < 16; o++) {
            float wv = wt[j * 16 + o];
            cv0[o] += wv * xr[kz][j];       // v0: plane kz
            cv1[o] += wv * xr[kz + 1][j];   // v1: plane kz+1
          }
        }
      }
    }
  }

  // memory channels (loaded late to shorten conv-phase live range)
  float xm0[16], xm1[16];
  {
    const float* o0p = sin + (size_t)gid0 * 32 + 16;
    const float* o1p = sin + (size_t)gid1 * 32 + 16;
#pragma unroll
    for (int c = 0; c < 16; c += 4) {
      float4 v0 = *(const float4*)(o0p + c);
      float4 v1 = *(const float4*)(o1p + c);
      xm0[c] = v0.x; xm0[c+1] = v0.y; xm0[c+2] = v0.z; xm0[c+3] = v0.w;
      xm1[c] = v1.x; xm1[c+1] = v1.y; xm1[c+2] = v1.z; xm1[c+3] = v1.w;
    }
  }

  // fc0 (relu) fused with fc1 accumulation; din = [xc | cv | xm]
  float dx0[32], dx1[32];
#pragma unroll
  for (int c = 0; c < 32; c++) { dx0[c] = 0.0f; dx1[c] = 0.0f; }
  for (int k = 0; k < 128; k++) {
    const float* w0 = f0w + k * 48;
    float bias = f0b[k];
    float a0 = bias, a1 = 0.0f, a2 = 0.0f, a3 = 0.0f;   // v0 partials
    float e0 = bias, e1 = 0.0f, e2 = 0.0f, e3 = 0.0f;   // v1 partials
#pragma unroll
    for (int c = 0; c < 16; c += 4) {
      float u0 = w0[c+0], u1 = w0[c+1], u2 = w0[c+2], u3 = w0[c+3];
      a0 += u0 * xc0[c+0]; a1 += u1 * xc0[c+1]; a2 += u2 * xc0[c+2]; a3 += u3 * xc0[c+3];
      e0 += u0 * xc1[c+0]; e1 += u1 * xc1[c+1]; e2 += u2 * xc1[c+2]; e3 += u3 * xc1[c+3];
    }
#pragma unroll
    for (int c = 0; c < 16; c += 4) {
      float u0 = w0[16+c+0], u1 = w0[16+c+1], u2 = w0[16+c+2], u3 = w0[16+c+3];
      a0 += u0 * cv0[c+0]; a1 += u1 * cv0[c+1]; a2 += u2 * cv0[c+2]; a3 += u3 * cv0[c+3];
      e0 += u0 * cv1[c+0]; e1 += u1 * cv1[c+1]; e2 += u2 * cv1[c+2]; e3 += u3 * cv1[c+3];
    }
#pragma unroll
    for (int c = 0; c < 16; c += 4) {
      float u0 = w0[32+c+0], u1 = w0[32+c+1], u2 = w0[32+c+2], u3 = w0[32+c+3];
      a0 += u0 * xm0[c+0]; a1 += u1 * xm0[c+1]; a2 += u2 * xm0[c+2]; a3 += u3 * xm0[c+3];
      e0 += u0 * xm1[c+0]; e1 += u1 * xm1[c+1]; e2 += u2 * xm1[c+2]; e3 += u3 * xm1[c+3];
    }
    float hk0 = fmaxf((a0 + a1) + (a2 + a3), 0.0f);
    float hk1 = fmaxf((e0 + e1) + (e2 + e3), 0.0f);
    const float* w1 = f1T + k * 32;
#pragma unroll
    for (int c = 0; c < 32; c++) {
      float wv = w1[c];
      dx0[c] += wv * hk0;
      dx1[c] += wv * hk1;
    }
  }

  // stochastic residual update; channel 0 frozen to OLD state
  float m0 = mask_val(k0, k1, (uint32_t)gid0);
  float m1 = mask_val(k0, k1, (uint32_t)gid1);
  float ov0[32], ov1[32];
  ov0[0] = xc0[0];
  ov1[0] = xc1[0];
#pragma unroll
  for (int c = 1; c < 16; c++)  { ov0[c] = fmaf(dx0[c], m0, xc0[c]);
                                  ov1[c] = fmaf(dx1[c], m1, xc1[c]); }
#pragma unroll
  for (int c = 16; c < 32; c++) { ov0[c] = fmaf(dx0[c], m0, xm0[c - 16]);
                                  ov1[c] = fmaf(dx1[c], m1, xm1[c - 16]); }
  float* po0 = sout + (size_t)gid0 * 32;
  float* po1 = sout + (size_t)gid1 * 32;
#pragma unroll
  for (int c = 0; c < 32; c += 4) {
    *(float4*)(po0 + c) = make_float4(ov0[c], ov0[c+1], ov0[c+2], ov0[c+3]);
    *(float4*)(po1 + c) = make_float4(ov1[c], ov1[c+1], ov1[c+2], ov1[c+3]);
  }
}

// ---------- final f32 state -> output (dtype per flag) ----------
__global__ __launch_bounds__(256) void nca_out(const float* __restrict__ st,
                                               void* __restrict__ out,
                                               const uint32_t* __restrict__ flagp) {
  uint32_t bf = *flagp;
  int gid = blockIdx.x * 256 + threadIdx.x;           // 4 elems/thread
  float4 v = *(const float4*)(st + (size_t)gid * 4);
  if (bf) {
    ushort4 u;
    u.x = f2bf(v.x); u.y = f2bf(v.y); u.z = f2bf(v.z); u.w = f2bf(v.w);
    *(ushort4*)((unsigned short*)out + (size_t)gid * 4) = u;
  } else {
    *(float4*)((float*)out + (size_t)gid * 4) = v;
  }
}

extern "C" void kernel_launch(void* const* d_in, const int* in_sizes, int n_in,
                              void* d_out, int out_size, void* d_ws, size_t ws_size,
                              hipStream_t stream) {
  float* ws = (float*)d_ws;
  float* sA = ws;
  float* sB = ws + NSTATE;
  float* wb = ws + 2 * NSTATE;
  uint32_t* flag = (uint32_t*)(ws + 2 * NSTATE + W_TOT);

  nca_detect<<<1, 256, 0, stream>>>((const uint32_t*)d_in[0], flag);
  nca_prep<<<68, 256, 0, stream>>>(d_in[1], d_in[2], d_in[3], d_in[4], d_in[5], wb, flag);
  nca_init<<<NVOX / 256, 256, 0, stream>>>(d_in[0], sA, flag);

  float* src = sA;
  float* dst = sB;
  for (int s = 0; s < 10; s++) {
    uint32_t o0, o1;
    tf2x32(0u, 42u, 0u, (uint32_t)s, o0, o1);   // folded step key, host-side
    nca_step<<<432, 256, 0, stream>>>(src, dst, wb, o0, o1);
    float* tmp = src; src = dst; dst = tmp;
  }
  nca_out<<<NSTATE / 4 / 256, 256, 0, stream>>>(src, d_out, flag);
}